// Round 15
// baseline (204.601 us; speedup 1.0000x reference)
//
#include <hip/hip_runtime.h>
#include <hip/hip_bf16.h>

#define BN 4
#define CC 256
#define C8 32
#define NN 4096
#define PROJ_ROWS 320

typedef __attribute__((ext_vector_type(8))) short short8;
typedef __attribute__((ext_vector_type(4))) float f32x4;
typedef __attribute__((ext_vector_type(4))) unsigned short u16x4;

__device__ __forceinline__ unsigned short f2bf(float f) {
    unsigned u = __builtin_bit_cast(unsigned, f);
    unsigned r = (u + 0x7fffu + ((u >> 16) & 1u)) >> 16;
    return (unsigned short)r;
}

__device__ __forceinline__ float bf2f(unsigned short s) {
    return __builtin_bit_cast(float, ((unsigned)s) << 16);
}

#define GL16(gsrc, ldst)                                                     \
    __builtin_amdgcn_global_load_lds(                                        \
        (const __attribute__((address_space(1))) void*)(gsrc),               \
        (__attribute__((address_space(3))) void*)(ldst), 16, 0, 0)

// ---------------------------------------------------------------------------
// Prep: W -> bf16 once (f2bf RNE -> bit-identical downstream).
// ---------------------------------------------------------------------------
__global__ __launch_bounds__(64) void prep_kernel(
    const float* __restrict__ Wq, const float* __restrict__ Wk,
    const float* __restrict__ Wv, unsigned short* __restrict__ Wb)
{
    int row = blockIdx.x;
    int l = threadIdx.x;
    const float* src = (row < 32) ? (Wq + (size_t)row * CC)
                     : (row < 64) ? (Wk + (size_t)(row - 32) * CC)
                                  : (Wv + (size_t)(row - 64) * CC);
    float4 v = *(const float4*)(src + l * 4);
    unsigned short t4[4] __attribute__((aligned(8)))
        = {f2bf(v.x), f2bf(v.y), f2bf(v.z), f2bf(v.w)};
    *(u16x4*)(Wb + (size_t)row * CC + l * 4) =
        (u16x4){t4[0], t4[1], t4[2], t4[3]};
}

// ---------------------------------------------------------------------------
// Projection GEMM (R12 version: n-tile 32, grid 512, Wb bf16 A-operands).
// ---------------------------------------------------------------------------
__global__ __launch_bounds__(256) void proj_kernel(
    const float* __restrict__ x, const unsigned short* __restrict__ Wb,
    const float* __restrict__ bq, const float* __restrict__ bk,
    const float* __restrict__ bv,
    unsigned short* __restrict__ proj, unsigned short* __restrict__ qT)
{
    int bid = blockIdx.x;
    int b = bid >> 7, nt = bid & 127;
    int n0 = nt * 32;
    int tid = threadIdx.x;
    int w = tid >> 6, l = tid & 63, l15 = l & 15, lq = l >> 4;

    __shared__ alignas(16) unsigned short Xt[32][264];

    int c_l = tid >> 3;
    int nb  = (tid & 7) * 4;

#pragma unroll
    for (int kc = 0; kc < 8; kc++) {
        const float* xp = x + ((size_t)(b * CC + kc * 32 + c_l)) * NN + n0 + nb;
        float4 x0 = *(const float4*)xp;
        float t[4] = {x0.x, x0.y, x0.z, x0.w};
#pragma unroll
        for (int e = 0; e < 4; e++) Xt[nb + e][kc * 32 + c_l] = f2bf(t[e]);
    }
    __syncthreads();

    f32x4 acc[5][2];
#pragma unroll
    for (int gi = 0; gi < 5; gi++)
#pragma unroll
        for (int mi = 0; mi < 2; mi++) acc[gi][mi] = (f32x4){0.f, 0.f, 0.f, 0.f};

    for (int kc = 0; kc < 8; kc++) {
#pragma unroll
        for (int gi = 0; gi < 5; gi++) {
            int og = (w * 5 + gi) * 16 + l15;
            short8 af = *(const short8*)(Wb + (size_t)og * CC + kc * 32 + lq * 8);
#pragma unroll
            for (int mi = 0; mi < 2; mi++) {
                short8 bf = *(const short8*)&Xt[mi * 16 + l15][kc * 32 + lq * 8];
                acc[gi][mi] = __builtin_amdgcn_mfma_f32_16x16x32_bf16(af, bf, acc[gi][mi], 0, 0, 0);
            }
        }
    }

#pragma unroll
    for (int gi = 0; gi < 5; gi++) {
#pragma unroll
        for (int r = 0; r < 4; r++) {
            int og = (w * 5 + gi) * 16 + lq * 4 + r;
            float bias = (og < 32) ? bq[og] : (og < 64) ? bk[og - 32] : bv[og - 64];
#pragma unroll
            for (int mi = 0; mi < 2; mi++) {
                int n = n0 + mi * 16 + l15;
                unsigned short v16 = f2bf(acc[gi][mi][r] + bias);
                if (og < 32) {
                    qT[((size_t)b * NN + n) * C8 + og] = v16;
                } else {
                    proj[((size_t)b * PROJ_ROWS + og) * NN + n] = v16;
                }
            }
        }
    }
}

// ---------------------------------------------------------------------------
// Flash attention, v15 = v9 core (68us winner, byte-identical loop + epilogue)
// + LAST-BLOCK FINALIZE: the NSPLIT h-blocks of each (b,mt) group share an
// XCD (bids differ only in bits 3-4).  After Opart/Lpart stores, each block
// fences and atomicAdds the group flag; the last arriver finalizes out for
// the whole 256c x 256m tile, reading the 4 Opart slices L2-hot.  No block
// waits -> no deadlock.  Eliminates the combine dispatch (R4-vs-R7 evidence:
// up to ~35us of the "side kernel" time is inter-dispatch overhead).
// ---------------------------------------------------------------------------
template<int NSPLIT, bool FINAL>
__global__ __launch_bounds__(1024, 4) void attn_kernel(
    const unsigned short* __restrict__ proj,
    const unsigned short* __restrict__ qT,
    const float* __restrict__ x,
    const float* __restrict__ gamma_p,
    float* __restrict__ out,
    unsigned short* __restrict__ Opart,
    float* __restrict__ Lpart,
    int* __restrict__ flags)
{
    constexpr int ITERS = 64 / NSPLIT;
    constexpr int LOGN  = (NSPLIT == 4) ? 2 : (NSPLIT == 2) ? 1 : 0;
    int bid = blockIdx.x;
    int xcd = bid & 7;
    int b   = xcd >> 1;
    int h   = (bid >> 3) & (NSPLIT - 1);
    int mt  = ((bid >> (3 + LOGN)) << 1) | (xcd & 1);   // 0..15
    int m0  = mt * 256;
    int nbase = h * (ITERS * 64);

    int tid = threadIdx.x;
    int w = tid >> 6, l = tid & 63, l15 = l & 15, lq = l >> 4;
    int wc = w & 3;        // c-quarter owner AND n16-slice owner for S
    int wm = w >> 2;       // m64 owner

    __shared__ alignas(16) unsigned short vlds[2][256 * 64];  // 64 KB
    __shared__ alignas(16) unsigned short qlds[2][2048];      // 8 KB
    __shared__ alignas(16) unsigned short ps[2][256][72];     // 72 KB
    __shared__ float red[4][256];
    __shared__ float Ltot[256];
    __shared__ int lastFlag;

    const unsigned short* kbase = proj + ((size_t)b * PROJ_ROWS + C8) * NN;
    const unsigned short* vbase = proj + ((size_t)b * PROJ_ROWS + 64) * NN;
    const unsigned short* qbase = qT + (size_t)b * NN * C8;

    // kfrag[mi]: B-operand k[c8 = lq*8+j][m = m0 + 64*wm + mi*16 + l15]
    short8 kfrag[4];
#pragma unroll
    for (int mi = 0; mi < 4; mi++) {
        int col = m0 + 64 * wm + mi * 16 + l15;
        unsigned short t8[8] __attribute__((aligned(16)));
#pragma unroll
        for (int j = 0; j < 8; j++)
            t8[j] = kbase[(size_t)(lq * 8 + j) * NN + col];
        kfrag[mi] = *(const short8*)t8;
    }

    // staging lane constants
    int vc_sub = l >> 3;               // c sub-row within 8-row group
    int vjsw   = (l & 7) ^ (l >> 3);   // source chunk (inverse swizzle)

    auto stageV = [&](int buf, int t) {
        int n0s = nbase + t * 64;
#pragma unroll
        for (int r = 0; r < 2; r++) {
            int crow = (r * 16 + w) * 8 + vc_sub;
            const unsigned short* src = vbase + (size_t)crow * NN + n0s + vjsw * 8;
            GL16(src, &vlds[buf][(r * 16 + w) * 512]);
        }
    };
    auto stageQ = [&](int buf, int t) {
        if (w < 4) {
            const unsigned short* src = qbase + (size_t)(nbase + t * 64) * C8 + (w * 64 + l) * 8;
            GL16(src, &qlds[buf][w * 512]);
        }
    };

    f32x4 O[4][4];
#pragma unroll
    for (int ci = 0; ci < 4; ci++)
#pragma unroll
        for (int mi = 0; mi < 4; mi++) O[ci][mi] = (f32x4){0.f, 0.f, 0.f, 0.f};
    float runS[4] = {0.f, 0.f, 0.f, 0.f};

    auto S_phase = [&](int pb, int qb) {
        short8 qfrag = *(const short8*)&qlds[qb][(16 * wc + l15) * 32 + lq * 8];
#pragma unroll
        for (int mi = 0; mi < 4; mi++) {
            f32x4 S = __builtin_amdgcn_mfma_f32_16x16x32_bf16(
                qfrag, kfrag[mi], (f32x4){0.f, 0.f, 0.f, 0.f}, 0, 0, 0);
            float p0 = __expf(S[0]);
            float p1 = __expf(S[1]);
            float p2 = __expf(S[2]);
            float p3 = __expf(S[3]);
            runS[mi] += (p0 + p1) + (p2 + p3);
            unsigned pk0 = (unsigned)f2bf(p0) | ((unsigned)f2bf(p1) << 16);
            unsigned pk1 = (unsigned)f2bf(p2) | ((unsigned)f2bf(p3) << 16);
            *(uint2*)&ps[pb][64 * wm + mi * 16 + l15][16 * wc + lq * 4]
                = make_uint2(pk0, pk1);
        }
    };

    // prologue: stage V(0), q(0), q(1); drain; S(0)
    stageV(0, 0);
    stageQ(0, 0);
    if (ITERS > 1) stageQ(1, 1);
    __syncthreads();
    S_phase(0, 0);

    for (int it = 0; it < ITERS; it++) {
        __syncthreads();   // ps[it&1]+V(it) ready; WAR on next buffers cleared

        if (it + 1 < ITERS) stageV((it + 1) & 1, it + 1);
        if (it + 2 < ITERS) stageQ((it + 2) & 1, it + 2);

        // PV: O[c,m] += V[c,n] . P[n,m]; wave (wc,wm) owns c64 x m64
        int vb = it & 1;
#pragma unroll
        for (int kh = 0; kh < 2; kh++) {
            short8 av[4];
#pragma unroll
            for (int ci = 0; ci < 4; ci++) {
                int c = 64 * wc + ci * 16 + l15;
                av[ci] = *(const short8*)&vlds[vb][c * 64 + (((kh * 4 + lq) ^ (c & 7)) * 8)];
            }
            short8 bfr[4];
#pragma unroll
            for (int mi = 0; mi < 4; mi++)
                bfr[mi] = *(const short8*)&ps[vb][64 * wm + mi * 16 + l15][kh * 32 + lq * 8];
#pragma unroll
            for (int ci = 0; ci < 4; ci++)
#pragma unroll
                for (int mi = 0; mi < 4; mi++)
                    O[ci][mi] = __builtin_amdgcn_mfma_f32_16x16x32_bf16(
                        av[ci], bfr[mi], O[ci][mi], 0, 0, 0);
        }

        if (it + 1 < ITERS) S_phase((it + 1) & 1, (it + 1) & 1);
    }

    // column sums: lane sums its 4 r-rows; shfl over lq; cross-wc via LDS
#pragma unroll
    for (int mi = 0; mi < 4; mi++) {
        float s2 = runS[mi];
        s2 += __shfl_xor(s2, 16);
        s2 += __shfl_xor(s2, 32);
        red[wc][64 * wm + mi * 16 + l15] = s2;
    }
    __syncthreads();

    if constexpr (FINAL) {
        if (tid < 256) Ltot[tid] = red[0][tid] + red[1][tid] + red[2][tid] + red[3][tid];
        __syncthreads();
        float gamma = gamma_p[0];
        float iv[4];
#pragma unroll
        for (int mi = 0; mi < 4; mi++) iv[mi] = 1.0f / Ltot[64 * wm + mi * 16 + l15];
#pragma unroll
        for (int ci = 0; ci < 4; ci++) {
#pragma unroll
            for (int mi = 0; mi < 4; mi++) {
                int m = m0 + 64 * wm + mi * 16 + l15;
#pragma unroll
                for (int r = 0; r < 4; r++) {
                    int c = 64 * wc + ci * 16 + lq * 4 + r;
                    size_t idx = ((size_t)b * CC + c) * NN + m;
                    out[idx] = gamma * (O[ci][mi][r] * iv[mi]) + x[idx];
                }
            }
        }
    } else {
        size_t p = ((size_t)h * BN + b) * 16 + mt;
        if (tid < 256)
            Lpart[p * 256 + tid] = red[0][tid] + red[1][tid] + red[2][tid] + red[3][tid];
        unsigned short* Ob = Opart + p * (size_t)(CC * 256);
#pragma unroll
        for (int ci = 0; ci < 4; ci++) {
#pragma unroll
            for (int mi = 0; mi < 4; mi++) {
#pragma unroll
                for (int r = 0; r < 4; r++) {
                    int c = 64 * wc + ci * 16 + lq * 4 + r;
                    int m = 64 * wm + mi * 16 + l15;
                    Ob[(size_t)c * 256 + m] = f2bf(O[ci][mi][r]);
                }
            }
        }

        // ---- last-block finalize (no waiting; device-scope flag) ----
        __syncthreads();
        if (tid == 0) {
            __threadfence();   // release our Opart/Lpart stores
            lastFlag = (atomicAdd(&flags[b * 16 + mt], 1) == NSPLIT - 1) ? 1 : 0;
        }
        __syncthreads();
        if (lastFlag) {
            __threadfence();   // acquire the other blocks' stores
            float gamma = gamma_p[0];
            int m4 = (tid & 63) * 4;
            int cgrp = tid >> 6;   // 0..15 (wave index)

            f32x4 Ls = (f32x4){0.f, 0.f, 0.f, 0.f};
#pragma unroll
            for (int h2 = 0; h2 < NSPLIT; h2++)
                Ls += *(const f32x4*)(Lpart + (((size_t)h2 * BN + b) * 16 + mt) * 256 + m4);
            f32x4 inv;
#pragma unroll
            for (int j = 0; j < 4; j++) inv[j] = 1.0f / Ls[j];

            for (int cp = 0; cp < 16; cp++) {
                int c = cp * 16 + cgrp;
                f32x4 acc = (f32x4){0.f, 0.f, 0.f, 0.f};
#pragma unroll
                for (int h2 = 0; h2 < NSPLIT; h2++) {
                    size_t p2 = ((size_t)h2 * BN + b) * 16 + mt;
                    u16x4 o4 = *(const u16x4*)(Opart + p2 * (size_t)(CC * 256)
                                               + (size_t)c * 256 + m4);
#pragma unroll
                    for (int j = 0; j < 4; j++) acc[j] += bf2f(o4[j]);
                }
                size_t idx = ((size_t)b * CC + c) * NN + mt * 256 + m4;
                f32x4 xv = *(const f32x4*)(x + idx);
                f32x4 o;
#pragma unroll
                for (int j = 0; j < 4; j++) o[j] = gamma * (acc[j] * inv[j]) + xv[j];
                *(f32x4*)(out + idx) = o;
            }
        }
    }
}

extern "C" void kernel_launch(void* const* d_in, const int* in_sizes, int n_in,
                              void* d_out, int out_size, void* d_ws, size_t ws_size,
                              hipStream_t stream) {
    const float* x     = (const float*)d_in[0];
    const float* Wq    = (const float*)d_in[1];
    const float* bq    = (const float*)d_in[2];
    const float* Wk    = (const float*)d_in[3];
    const float* bk    = (const float*)d_in[4];
    const float* Wv    = (const float*)d_in[5];
    const float* bv    = (const float*)d_in[6];
    const float* gamma = (const float*)d_in[7];
    float* out = (float*)d_out;
    (void)in_sizes; (void)n_in; (void)out_size;

    unsigned short* proj = (unsigned short*)d_ws;
    unsigned short* qT   = proj + (size_t)BN * PROJ_ROWS * NN;
    unsigned short* Wb   = qT + (size_t)BN * NN * C8;
    const size_t baseB = ((size_t)BN * PROJ_ROWS * NN + (size_t)BN * NN * C8) * 2
                       + (size_t)PROJ_ROWS * CC * 2;

    auto needB = [&](int ns) {
        size_t LpB = (size_t)ns * BN * 16 * 256 * 4;
        size_t OpB = (size_t)ns * BN * 16 * CC * 256 * 2;   // bf16 Opart
        return baseB + LpB + OpB + 64 * sizeof(int);        // + flags
    };

    prep_kernel<<<320, 64, 0, stream>>>(Wq, Wk, Wv, Wb);
    proj_kernel<<<512, 256, 0, stream>>>(x, Wb, bq, bk, bv, proj, qT);

    if (ws_size >= needB(4)) {
        float* Lpart = (float*)((char*)d_ws + baseB);
        unsigned short* Opart = (unsigned short*)(Lpart + (size_t)4 * BN * 16 * 256);
        int* flags = (int*)(Opart + (size_t)4 * BN * 16 * CC * 256);
        hipMemsetAsync(flags, 0, 64 * sizeof(int), stream);
        attn_kernel<4, false><<<256, 1024, 0, stream>>>(proj, qT, x, gamma, out,
                                                        Opart, Lpart, flags);
    } else if (ws_size >= needB(2)) {
        float* Lpart = (float*)((char*)d_ws + baseB);
        unsigned short* Opart = (unsigned short*)(Lpart + (size_t)2 * BN * 16 * 256);
        int* flags = (int*)(Opart + (size_t)2 * BN * 16 * CC * 256);
        hipMemsetAsync(flags, 0, 64 * sizeof(int), stream);
        attn_kernel<2, false><<<128, 1024, 0, stream>>>(proj, qT, x, gamma, out,
                                                        Opart, Lpart, flags);
    } else {
        attn_kernel<1, true><<<64, 1024, 0, stream>>>(proj, qT, x, gamma, out,
                                                      nullptr, nullptr, nullptr);
    }
}

// Round 16
// 162.412 us; speedup vs baseline: 1.2598x; 1.2598x over previous
//
#include <hip/hip_runtime.h>
#include <hip/hip_bf16.h>

#define BN 4
#define CC 256
#define C8 32
#define NN 4096
#define PROJ_ROWS 320

typedef __attribute__((ext_vector_type(8))) short short8;
typedef __attribute__((ext_vector_type(4))) float f32x4;
typedef __attribute__((ext_vector_type(4))) unsigned short u16x4;

__device__ __forceinline__ unsigned short f2bf(float f) {
    unsigned u = __builtin_bit_cast(unsigned, f);
    unsigned r = (u + 0x7fffu + ((u >> 16) & 1u)) >> 16;
    return (unsigned short)r;
}

__device__ __forceinline__ float bf2f(unsigned short s) {
    return __builtin_bit_cast(float, ((unsigned)s) << 16);
}

#define GL16(gsrc, ldst)                                                     \
    __builtin_amdgcn_global_load_lds(                                        \
        (const __attribute__((address_space(1))) void*)(gsrc),               \
        (__attribute__((address_space(3))) void*)(ldst), 16, 0, 0)

// ---------------------------------------------------------------------------
// Projection GEMM (R11 config, best measured total 163.6us): MFMA core with
// runtime W conversion; epilogue transposes fragments through the dead Xt
// LDS and stores full 128B rows (short8/lane); qT in [n][og] order.
// ---------------------------------------------------------------------------
__global__ __launch_bounds__(256) void proj_kernel(
    const float* __restrict__ x,
    const float* __restrict__ Wq, const float* __restrict__ bq,
    const float* __restrict__ Wk, const float* __restrict__ bk,
    const float* __restrict__ Wv, const float* __restrict__ bv,
    unsigned short* __restrict__ proj, unsigned short* __restrict__ qT)
{
    int bid = blockIdx.x;
    int b = bid >> 6, nt = bid & 63;
    int n0 = nt * 64;
    int tid = threadIdx.x;
    int w = tid >> 6, l = tid & 63, l15 = l & 15, lq = l >> 4;

    __shared__ alignas(16) unsigned short Xt[64][264];

    int c_l = tid >> 3;          // 0..31
    int nb  = (tid & 7) * 8;     // 0..56

#pragma unroll
    for (int kc = 0; kc < 8; kc++) {
        const float* xp = x + ((size_t)(b * CC + kc * 32 + c_l)) * NN + n0 + nb;
        float4 x0 = *(const float4*)xp;
        float4 x1 = *(const float4*)(xp + 4);
        float t[8] = {x0.x, x0.y, x0.z, x0.w, x1.x, x1.y, x1.z, x1.w};
#pragma unroll
        for (int e = 0; e < 8; e++) Xt[nb + e][kc * 32 + c_l] = f2bf(t[e]);
    }
    __syncthreads();

    f32x4 acc[5][4];
#pragma unroll
    for (int gi = 0; gi < 5; gi++)
#pragma unroll
        for (int mi = 0; mi < 4; mi++) acc[gi][mi] = (f32x4){0.f, 0.f, 0.f, 0.f};

    for (int kc = 0; kc < 8; kc++) {
        float4 wf[5][2];
#pragma unroll
        for (int gi = 0; gi < 5; gi++) {
            int og = (w * 5 + gi) * 16 + l15;
            const float* wrow = (og < 32) ? (Wq + (size_t)og * CC)
                              : (og < 64) ? (Wk + (size_t)(og - 32) * CC)
                                          : (Wv + (size_t)(og - 64) * CC);
            const float* wp = wrow + kc * 32 + lq * 8;
            wf[gi][0] = *(const float4*)wp;
            wf[gi][1] = *(const float4*)(wp + 4);
        }
#pragma unroll
        for (int gi = 0; gi < 5; gi++) {
            unsigned short a8[8] __attribute__((aligned(16)));
            float tw[8] = {wf[gi][0].x, wf[gi][0].y, wf[gi][0].z, wf[gi][0].w,
                           wf[gi][1].x, wf[gi][1].y, wf[gi][1].z, wf[gi][1].w};
#pragma unroll
            for (int e = 0; e < 8; e++) a8[e] = f2bf(tw[e]);
            short8 af = *(const short8*)a8;
#pragma unroll
            for (int mi = 0; mi < 4; mi++) {
                short8 bf = *(const short8*)&Xt[mi * 16 + l15][kc * 32 + lq * 8];
                acc[gi][mi] = __builtin_amdgcn_mfma_f32_16x16x32_bf16(af, bf, acc[gi][mi], 0, 0, 0);
            }
        }
    }

    // ---- coalesced epilogue: two passes of 160 og-rows through T (=Xt) ----
    __syncthreads();   // Xt reads done; reuse storage
    unsigned short (*T)[72] = reinterpret_cast<unsigned short(*)[72]>(&Xt[0][0]);

#pragma unroll
    for (int pass = 0; pass < 2; pass++) {
        if ((w >> 1) == pass) {
#pragma unroll
            for (int gi = 0; gi < 5; gi++) {
#pragma unroll
                for (int r = 0; r < 4; r++) {
                    int og = (w * 5 + gi) * 16 + lq * 4 + r;
                    float bias = (og < 32) ? bq[og] : (og < 64) ? bk[og - 32] : bv[og - 64];
                    int ogp = og - pass * 160;
#pragma unroll
                    for (int mi = 0; mi < 4; mi++)
                        T[ogp][mi * 16 + l15] = f2bf(acc[gi][mi][r] + bias);
                }
            }
        }
        __syncthreads();

        if (pass == 0) {
            // qT: og 0..31, layout [n][og]; 4 lanes complete each 64B line
            {
                int n = tid >> 2, o8 = (tid & 3) * 8;
                unsigned short t8[8] __attribute__((aligned(16)));
#pragma unroll
                for (int j = 0; j < 8; j++) t8[j] = T[o8 + j][n];
                *(short8*)(qT + ((size_t)b * NN + n0 + n) * C8 + o8) = *(short8*)t8;
            }
            // proj rows og 32..159: 128B contiguous per row (8 lanes x 16B)
#pragma unroll
            for (int step = 0; step < 4; step++) {
                int row = 32 + step * 32 + (tid >> 3);
                int n8 = (tid & 7) * 8;
                short8 v = *(const short8*)&T[row][n8];
                *(short8*)(proj + ((size_t)b * PROJ_ROWS + row) * NN + n0 + n8) = v;
            }
            __syncthreads();   // WAR before pass-1 writes T
        } else {
            // proj rows og 160..319
#pragma unroll
            for (int step = 0; step < 5; step++) {
                int row = step * 32 + (tid >> 3);
                int n8 = (tid & 7) * 8;
                short8 v = *(const short8*)&T[row][n8];
                *(short8*)(proj + ((size_t)b * PROJ_ROWS + 160 + row) * NN + n0 + n8) = v;
            }
        }
    }
}

// ---------------------------------------------------------------------------
// Flash attention, v9 (68us winner): 1024-thread block (16 waves, m-tile
// 256), V+q staged in LDS via async global_load_lds so each V tile is
// requested ONCE per CU-iteration.
// ---------------------------------------------------------------------------
template<int NSPLIT, bool FINAL>
__global__ __launch_bounds__(1024, 4) void attn_kernel(
    const unsigned short* __restrict__ proj,
    const unsigned short* __restrict__ qT,
    const float* __restrict__ x,
    const float* __restrict__ gamma_p,
    float* __restrict__ out,
    unsigned short* __restrict__ Opart,
    float* __restrict__ Lpart)
{
    constexpr int ITERS = 64 / NSPLIT;
    constexpr int LOGN  = (NSPLIT == 4) ? 2 : (NSPLIT == 2) ? 1 : 0;
    int bid = blockIdx.x;
    int xcd = bid & 7;
    int b   = xcd >> 1;
    int h   = (bid >> 3) & (NSPLIT - 1);
    int mt  = ((bid >> (3 + LOGN)) << 1) | (xcd & 1);   // 0..15
    int m0  = mt * 256;
    int nbase = h * (ITERS * 64);

    int tid = threadIdx.x;
    int w = tid >> 6, l = tid & 63, l15 = l & 15, lq = l >> 4;
    int wc = w & 3;        // c-quarter owner AND n16-slice owner for S
    int wm = w >> 2;       // m64 owner

    __shared__ alignas(16) unsigned short vlds[2][256 * 64];  // 64 KB
    __shared__ alignas(16) unsigned short qlds[2][2048];      // 8 KB
    __shared__ alignas(16) unsigned short ps[2][256][72];     // 72 KB
    __shared__ float red[4][256];
    __shared__ float Ltot[256];

    const unsigned short* kbase = proj + ((size_t)b * PROJ_ROWS + C8) * NN;
    const unsigned short* vbase = proj + ((size_t)b * PROJ_ROWS + 64) * NN;
    const unsigned short* qbase = qT + (size_t)b * NN * C8;

    // kfrag[mi]: B-operand k[c8 = lq*8+j][m = m0 + 64*wm + mi*16 + l15]
    short8 kfrag[4];
#pragma unroll
    for (int mi = 0; mi < 4; mi++) {
        int col = m0 + 64 * wm + mi * 16 + l15;
        unsigned short t8[8] __attribute__((aligned(16)));
#pragma unroll
        for (int j = 0; j < 8; j++)
            t8[j] = kbase[(size_t)(lq * 8 + j) * NN + col];
        kfrag[mi] = *(const short8*)t8;
    }

    // staging lane constants
    int vc_sub = l >> 3;               // c sub-row within 8-row group
    int vjsw   = (l & 7) ^ (l >> 3);   // source chunk (inverse swizzle)

    // stage V tile (32 KB, 2 rounds x 16 waves x 1 KB) for n-tile t -> vlds[buf]
    auto stageV = [&](int buf, int t) {
        int n0s = nbase + t * 64;
#pragma unroll
        for (int r = 0; r < 2; r++) {
            int crow = (r * 16 + w) * 8 + vc_sub;
            const unsigned short* src = vbase + (size_t)crow * NN + n0s + vjsw * 8;
            GL16(src, &vlds[buf][(r * 16 + w) * 512]);
        }
    };
    // stage q tile (4 KB, waves 0..3) for n-tile t -> qlds[buf]
    auto stageQ = [&](int buf, int t) {
        if (w < 4) {
            const unsigned short* src = qbase + (size_t)(nbase + t * 64) * C8 + (w * 64 + l) * 8;
            GL16(src, &qlds[buf][w * 512]);
        }
    };

    f32x4 O[4][4];
#pragma unroll
    for (int ci = 0; ci < 4; ci++)
#pragma unroll
        for (int mi = 0; mi < 4; mi++) O[ci][mi] = (f32x4){0.f, 0.f, 0.f, 0.f};
    float runS[4] = {0.f, 0.f, 0.f, 0.f};

    // S phase: compute S(n16 of wc x m64 of wm) from qlds[qb], write ps[pb]
    auto S_phase = [&](int pb, int qb) {
        short8 qfrag = *(const short8*)&qlds[qb][(16 * wc + l15) * 32 + lq * 8];
#pragma unroll
        for (int mi = 0; mi < 4; mi++) {
            f32x4 S = __builtin_amdgcn_mfma_f32_16x16x32_bf16(
                qfrag, kfrag[mi], (f32x4){0.f, 0.f, 0.f, 0.f}, 0, 0, 0);
            float p0 = __expf(S[0]);
            float p1 = __expf(S[1]);
            float p2 = __expf(S[2]);
            float p3 = __expf(S[3]);
            runS[mi] += (p0 + p1) + (p2 + p3);
            unsigned pk0 = (unsigned)f2bf(p0) | ((unsigned)f2bf(p1) << 16);
            unsigned pk1 = (unsigned)f2bf(p2) | ((unsigned)f2bf(p3) << 16);
            *(uint2*)&ps[pb][64 * wm + mi * 16 + l15][16 * wc + lq * 4]
                = make_uint2(pk0, pk1);
        }
    };

    // prologue: stage V(0), q(0), q(1); drain; S(0)
    stageV(0, 0);
    stageQ(0, 0);
    if (ITERS > 1) stageQ(1, 1);
    __syncthreads();
    S_phase(0, 0);

    for (int it = 0; it < ITERS; it++) {
        __syncthreads();   // ps[it&1]+V(it) ready; WAR on next buffers cleared

        if (it + 1 < ITERS) stageV((it + 1) & 1, it + 1);
        if (it + 2 < ITERS) stageQ((it + 2) & 1, it + 2);

        // PV: O[c,m] += V[c,n] . P[n,m]; wave (wc,wm) owns c64 x m64
        int vb = it & 1;
#pragma unroll
        for (int kh = 0; kh < 2; kh++) {
            short8 av[4];
#pragma unroll
            for (int ci = 0; ci < 4; ci++) {
                int c = 64 * wc + ci * 16 + l15;
                av[ci] = *(const short8*)&vlds[vb][c * 64 + (((kh * 4 + lq) ^ (c & 7)) * 8)];
            }
            short8 bfr[4];
#pragma unroll
            for (int mi = 0; mi < 4; mi++)
                bfr[mi] = *(const short8*)&ps[vb][64 * wm + mi * 16 + l15][kh * 32 + lq * 8];
#pragma unroll
            for (int ci = 0; ci < 4; ci++)
#pragma unroll
                for (int mi = 0; mi < 4; mi++)
                    O[ci][mi] = __builtin_amdgcn_mfma_f32_16x16x32_bf16(
                        av[ci], bfr[mi], O[ci][mi], 0, 0, 0);
        }

        // S(it+1) from qlds[(it+1)&1] (staged at iter it-1, drained at barrier)
        if (it + 1 < ITERS) S_phase((it + 1) & 1, (it + 1) & 1);
    }

    // column sums: lane sums its 4 r-rows; shfl over lq; cross-wc via LDS
#pragma unroll
    for (int mi = 0; mi < 4; mi++) {
        float s2 = runS[mi];
        s2 += __shfl_xor(s2, 16);
        s2 += __shfl_xor(s2, 32);
        red[wc][64 * wm + mi * 16 + l15] = s2;
    }
    __syncthreads();

    if constexpr (FINAL) {
        if (tid < 256) Ltot[tid] = red[0][tid] + red[1][tid] + red[2][tid] + red[3][tid];
        __syncthreads();
        float gamma = gamma_p[0];
        float iv[4];
#pragma unroll
        for (int mi = 0; mi < 4; mi++) iv[mi] = 1.0f / Ltot[64 * wm + mi * 16 + l15];
#pragma unroll
        for (int ci = 0; ci < 4; ci++) {
#pragma unroll
            for (int mi = 0; mi < 4; mi++) {
                int m = m0 + 64 * wm + mi * 16 + l15;
#pragma unroll
                for (int r = 0; r < 4; r++) {
                    int c = 64 * wc + ci * 16 + lq * 4 + r;
                    size_t idx = ((size_t)b * CC + c) * NN + m;
                    out[idx] = gamma * (O[ci][mi][r] * iv[mi]) + x[idx];
                }
            }
        }
    } else {
        size_t p = ((size_t)h * BN + b) * 16 + mt;
        if (tid < 256)
            Lpart[p * 256 + tid] = red[0][tid] + red[1][tid] + red[2][tid] + red[3][tid];
        unsigned short* Ob = Opart + p * (size_t)(CC * 256);
#pragma unroll
        for (int ci = 0; ci < 4; ci++) {
#pragma unroll
            for (int mi = 0; mi < 4; mi++) {
#pragma unroll
                for (int r = 0; r < 4; r++) {
                    int c = 64 * wc + ci * 16 + lq * 4 + r;
                    int m = 64 * wm + mi * 16 + l15;
                    Ob[(size_t)c * 256 + m] = f2bf(O[ci][mi][r]);
                }
            }
        }
    }
}

// ---------------------------------------------------------------------------
// Combine: out = gamma * (sum_h O_h) / (sum_h L_h) + x.  Opart is bf16,
// [p][c 256][m 256].  Grid 512: one block per (b, mt16, c-eighth).
// ---------------------------------------------------------------------------
template<int NSPLIT>
__global__ __launch_bounds__(256) void combine_kernel(
    const unsigned short* __restrict__ Opart, const float* __restrict__ Lpart,
    const float* __restrict__ x, const float* __restrict__ gamma_p,
    float* __restrict__ out)
{
    int bid = blockIdx.x;
    int cq = bid & 7;
    int mt = (bid >> 3) & 15;
    int b  = bid >> 7;
    int tid = threadIdx.x;
    int m4 = (tid & 63) * 4;     // m offset (f32x4 over 256 m)
    int ci4 = tid >> 6;          // c sub-index 0..3
    float gamma = gamma_p[0];

    f32x4 Ls = (f32x4){0.f, 0.f, 0.f, 0.f};
#pragma unroll
    for (int h = 0; h < NSPLIT; h++) {
        size_t p = ((size_t)h * BN + b) * 16 + mt;
        Ls += *(const f32x4*)(Lpart + p * 256 + m4);
    }
    f32x4 inv;
#pragma unroll
    for (int j = 0; j < 4; j++) inv[j] = 1.0f / Ls[j];

#pragma unroll
    for (int cp = 0; cp < 8; cp++) {
        int c = cq * 32 + cp * 4 + ci4;
        f32x4 acc = (f32x4){0.f, 0.f, 0.f, 0.f};
#pragma unroll
        for (int h = 0; h < NSPLIT; h++) {
            size_t p = ((size_t)h * BN + b) * 16 + mt;
            u16x4 o4 = *(const u16x4*)(Opart + p * (size_t)(CC * 256) + (size_t)c * 256 + m4);
#pragma unroll
            for (int j = 0; j < 4; j++) acc[j] += bf2f(o4[j]);
        }
        size_t idx = ((size_t)b * CC + c) * NN + mt * 256 + m4;
        f32x4 xv = *(const f32x4*)(x + idx);
        f32x4 o;
#pragma unroll
        for (int j = 0; j < 4; j++) o[j] = gamma * (acc[j] * inv[j]) + xv[j];
        *(f32x4*)(out + idx) = o;
    }
}

extern "C" void kernel_launch(void* const* d_in, const int* in_sizes, int n_in,
                              void* d_out, int out_size, void* d_ws, size_t ws_size,
                              hipStream_t stream) {
    const float* x     = (const float*)d_in[0];
    const float* Wq    = (const float*)d_in[1];
    const float* bq    = (const float*)d_in[2];
    const float* Wk    = (const float*)d_in[3];
    const float* bk    = (const float*)d_in[4];
    const float* Wv    = (const float*)d_in[5];
    const float* bv    = (const float*)d_in[6];
    const float* gamma = (const float*)d_in[7];
    float* out = (float*)d_out;
    (void)in_sizes; (void)n_in; (void)out_size;

    unsigned short* proj = (unsigned short*)d_ws;
    unsigned short* qT   = proj + (size_t)BN * PROJ_ROWS * NN;
    const size_t baseB = ((size_t)BN * PROJ_ROWS * NN + (size_t)BN * NN * C8) * 2;

    auto needB = [&](int ns) {
        size_t LpB = (size_t)ns * BN * 16 * 256 * 4;
        size_t OpB = (size_t)ns * BN * 16 * CC * 256 * 2;   // bf16 Opart
        return baseB + LpB + OpB;
    };

    proj_kernel<<<256, 256, 0, stream>>>(x, Wq, bq, Wk, bk, Wv, bv, proj, qT);

    if (ws_size >= needB(4)) {
        float* Lpart = (float*)((char*)d_ws + baseB);
        unsigned short* Opart = (unsigned short*)(Lpart + (size_t)4 * BN * 16 * 256);
        attn_kernel<4, false><<<256, 1024, 0, stream>>>(proj, qT, x, gamma, out, Opart, Lpart);
        combine_kernel<4><<<512, 256, 0, stream>>>(Opart, Lpart, x, gamma, out);
    } else if (ws_size >= needB(2)) {
        float* Lpart = (float*)((char*)d_ws + baseB);
        unsigned short* Opart = (unsigned short*)(Lpart + (size_t)2 * BN * 16 * 256);
        attn_kernel<2, false><<<128, 1024, 0, stream>>>(proj, qT, x, gamma, out, Opart, Lpart);
        combine_kernel<2><<<512, 256, 0, stream>>>(Opart, Lpart, x, gamma, out);
    } else {
        attn_kernel<1, true><<<64, 1024, 0, stream>>>(proj, qT, x, gamma, out, nullptr, nullptr);
    }
}